// Round 8
// baseline (126.255 us; speedup 1.0000x reference)
//
#include <hip/hip_runtime.h>

typedef _Float16 f16x8 __attribute__((ext_vector_type(8)));
typedef float f32x16 __attribute__((ext_vector_type(16)));

#define V_TOTAL 8192
#define C_DIM   64
#define N_TOK   32768
#define INV2048 4.8828125e-4f
#define THR_COEF 2.2e-3f

// pass1: VSPLIT1=4 segs of 2048 codes, chunks of 64 codes (2 MFMA tiles)
#define VSPLIT1 4
#define VSEG1   2048
#define CH1     32          // 2048/64
// pass2: VSPLIT2=8 segs of 1024 codes, chunks of 32 codes
#define VSPLIT2 8
#define VSEG2   1024
#define CH2     32

typedef const __attribute__((address_space(1))) _Float16 glb_f16;
typedef __attribute__((address_space(3))) _Float16 lds_f16;

// ws float offsets:
//   cp       f16[1048576]  @ 0         (2 MiB) packed split codes (hi term0, lo term1)
//            offset = cvg*4096 + term*2048 + q*256 + c*8   (granule cvg = 32 codes)
//   m1s      f32[4][32768] @ 524288
//   m2s      f32[4][32768] @ 655360
//   i1s      int[4][32768] @ 786432
//   fn2      f32[32768]    @ 917504
//   keys     u64[32768]    @ 950272
//   idxf     int[32768]    @ 1015808
//   unc_list int[32768]    @ 1048576
//   unc_cnt  int           @ 1081344
//   counts   int[8192]     @ 1081408
//   blocksq  f32[128]      @ 1089600

__device__ __forceinline__ unsigned long long packkey(float s, int idx) {
    unsigned u = __float_as_uint(s);
    unsigned k = u ^ ((unsigned)(((int)u) >> 31) | 0x80000000u);
    return ((unsigned long long)k << 32) | (unsigned)(8191 - idx);
}

__global__ __launch_bounds__(256)
void k_prep(const float* __restrict__ w, _Float16* __restrict__ cp,
            unsigned long long* __restrict__ keys, int* __restrict__ counts,
            int* __restrict__ unc_cnt) {
    int v = blockIdx.x * 256 + threadIdx.x;   // one code per thread
    counts[v] = 0;
    if (v == 0) unc_cnt[0] = 0;
#pragma unroll
    for (int i = 0; i < 4; ++i) keys[v * 4 + i] = 0ull;
    const float4* row = (const float4*)(w + v * C_DIM);
    float4 r[16];
    float s = 0.f;
#pragma unroll
    for (int i = 0; i < 16; ++i) {
        r[i] = row[i];
        s += r[i].x * r[i].x + r[i].y * r[i].y + r[i].z * r[i].z + r[i].w * r[i].w;
    }
    float inv = 1.0f / fmaxf(sqrtf(s), 1e-12f);
    const float* rs = (const float*)r;
    const int cv = v >> 5, c = v & 31;
#pragma unroll
    for (int q = 0; q < 8; ++q) {
        f16x8 hi, lo;
#pragma unroll
        for (int j = 0; j < 8; ++j) {
            float x = rs[q * 8 + j] * inv;
            _Float16 h = (_Float16)x;
            hi[j] = h;
            lo[j] = (_Float16)((x - (float)h) * 2048.0f);
        }
        *(f16x8*)(cp + cv * 4096 +        q * 256 + c * 8) = hi;
        *(f16x8*)(cp + cv * 4096 + 2048 + q * 256 + c * 8) = lo;
    }
}

// Pass 1: hi-only screen. 4 waves/block, 32 tokens/wave, 64-code chunks via LDS,
// 3-ahead counted-vmcnt staging. Tracks per-token top-1 (val,idx) + top-2 val.
__global__ __launch_bounds__(256, 4)
void k_pass1(const float* __restrict__ f, const _Float16* __restrict__ cp,
             float* __restrict__ m1s, float* __restrict__ m2s,
             int* __restrict__ i1s, float* __restrict__ fn2) {
    __shared__ __align__(16) _Float16 lds[4][4096];   // 4 x 8 KiB (64 codes hi)

    const int tid  = threadIdx.x;
    const int lane = tid & 63;
    const int wid  = tid >> 6;
    const int c31  = lane & 31;
    const int g    = lane >> 5;
    const int seg  = blockIdx.y;
    const int t0   = blockIdx.x * 128 + wid * 32;

    // B (token) hi fragments + ||f||^2 partial
    f16x8 bh[4];
    float s2 = 0.f;
    {
        const int T = t0 + c31;
        const float* fb = f + (T >> 10) * 65536 + (T & 1023);
#pragma unroll
        for (int ks = 0; ks < 4; ++ks) {
#pragma unroll
            for (int j = 0; j < 8; ++j) {
                float v = fb[(ks * 16 + g * 8 + j) * 1024];
                s2 += v * v;
                bh[ks][j] = (_Float16)v;
            }
        }
    }

    const _Float16* seg_cp = cp + (size_t)seg * (VSEG1 / 32) * 4096;

    // stage 64-code chunk cv (hi halves of granules 2cv, 2cv+1) into lds[cv&3]
    auto stage = [&](int cv) {
        const _Float16* s0 = seg_cp + (2 * cv + 0) * 4096 + wid * 512 + lane * 8;
        const _Float16* s1 = seg_cp + (2 * cv + 1) * 4096 + wid * 512 + lane * 8;
        _Float16* d0 = &lds[cv & 3][wid * 512];
        _Float16* d1 = &lds[cv & 3][2048 + wid * 512];
        __builtin_amdgcn_global_load_lds((glb_f16*)s0, (lds_f16*)d0, 16, 0, 0);
        __builtin_amdgcn_global_load_lds((glb_f16*)s1, (lds_f16*)d1, 16, 0, 0);
    };

    const f32x16 zacc = {0.f,0.f,0.f,0.f,0.f,0.f,0.f,0.f,0.f,0.f,0.f,0.f,0.f,0.f,0.f,0.f};

    float m1 = -3.4e38f, m2 = -3.4e38f;
    int   i1 = 0;    // code' without +4g

    stage(0); stage(1); stage(2);

#pragma unroll 1
    for (int cv = 0; cv < CH1; ++cv) {
        if (cv < CH1 - 2)       asm volatile("s_waitcnt vmcnt(4)" ::: "memory");
        else if (cv == CH1 - 2) asm volatile("s_waitcnt vmcnt(2)" ::: "memory");
        else                    asm volatile("s_waitcnt vmcnt(0)" ::: "memory");
        __builtin_amdgcn_s_barrier();
        if (cv + 3 < CH1) stage(cv + 3);

        const _Float16* base = &lds[cv & 3][g * 256 + c31 * 8];
#pragma unroll
        for (int tile = 0; tile < 2; ++tile) {
            const _Float16* tb = base + tile * 2048;
            f16x8 A0 = *(const f16x8*)(tb);
            f16x8 A1 = *(const f16x8*)(tb + 512);
            f16x8 A2 = *(const f16x8*)(tb + 1024);
            f16x8 A3 = *(const f16x8*)(tb + 1536);
            f32x16 amA, amB;
            amA = __builtin_amdgcn_mfma_f32_32x32x16_f16(A0, bh[0], zacc, 0, 0, 0);
            amB = __builtin_amdgcn_mfma_f32_32x32x16_f16(A2, bh[2], zacc, 0, 0, 0);
            amA = __builtin_amdgcn_mfma_f32_32x32x16_f16(A1, bh[1], amA, 0, 0, 0);
            amB = __builtin_amdgcn_mfma_f32_32x32x16_f16(A3, bh[3], amB, 0, 0, 0);

            const int codebase = seg * VSEG1 + cv * 64 + tile * 32;   // SGPR
#pragma unroll
            for (int r = 0; r < 16; ++r) {
                const int codeq = codebase + (r & 3) + 8 * (r >> 2);
                float s = amA[r] + amB[r];
                float nm2 = __builtin_amdgcn_fmed3f(m1, m2, s);  // 2nd-largest of {m1,m2,s}
                bool u = s > m1;
                i1 = u ? codeq : i1;
                m1 = fmaxf(m1, s);
                m2 = nm2;
            }
        }
    }

    i1 += 4 * g;
    // pair-merge (lane, lane^32): top-2 of union
    {
        float om1 = __shfl_xor(m1, 32);
        float om2 = __shfl_xor(m2, 32);
        int   oi1 = __shfl_xor(i1, 32);
        float nm2 = fmaxf(fminf(m1, om1), fmaxf(m2, om2));
        bool rep = om1 > m1;
        i1 = rep ? oi1 : i1;
        m1 = fmaxf(m1, om1);
        m2 = nm2;
        float os2 = __shfl_xor(s2, 32);
        s2 += os2;
    }
    if (lane < 32) {
        const int t = t0 + c31;
        m1s[seg * N_TOK + t] = m1;
        m2s[seg * N_TOK + t] = m2;
        i1s[seg * N_TOK + t] = i1;
        fn2[t] = s2;    // all segs write identical value
    }
}

__global__ __launch_bounds__(256)
void k_classify(const float* __restrict__ m1s, const float* __restrict__ m2s,
                const int* __restrict__ i1s, const float* __restrict__ fn2,
                int* __restrict__ idxf, int* __restrict__ unc_list,
                int* __restrict__ unc_cnt) {
    const int t = blockIdx.x * 256 + threadIdx.x;
    float a1 = m1s[t], a2 = m2s[t];
    int   ai = i1s[t];
#pragma unroll
    for (int s = 1; s < VSPLIT1; ++s) {
        float b1 = m1s[s * N_TOK + t];
        float b2 = m2s[s * N_TOK + t];
        int   bi = i1s[s * N_TOK + t];
        float na2 = fmaxf(fminf(a1, b1), fmaxf(a2, b2));
        bool rep = b1 > a1;
        ai = rep ? bi : ai;
        a1 = fmaxf(a1, b1);
        a2 = na2;
    }
    const float thr = THR_COEF * sqrtf(fn2[t]);
    if (a1 - a2 > thr) {
        idxf[t] = ai;            // provably the exact f32 argmax
    } else {
        idxf[t] = -1;
        int pos = atomicAdd(unc_cnt, 1);
        unc_list[pos] = t;
    }
}

// Pass 2: exact 3-MFMA (hi+lo) rescore of uncertain tokens over ALL codes.
// grid (256 group-slots, 8 segs), 1 wave/block, grid-stride over groups.
__global__ __launch_bounds__(64, 2)
void k_pass2(const float* __restrict__ f, const _Float16* __restrict__ cp,
             const int* __restrict__ unc_list, const int* __restrict__ unc_cnt,
             unsigned long long* __restrict__ keys) {
    const int lane = threadIdx.x;
    const int c31  = lane & 31;
    const int g    = lane >> 5;
    const int seg  = blockIdx.y;

    const int n = unc_cnt[0];
    const int ngroups = (n + 31) >> 5;
    const f32x16 zacc = {0.f,0.f,0.f,0.f,0.f,0.f,0.f,0.f,0.f,0.f,0.f,0.f,0.f,0.f,0.f,0.f};

    for (int grp = blockIdx.x; grp < ngroups; grp += 256) {
        int j = grp * 32 + c31;
        if (j >= n) j = n - 1;
        const int T = unc_list[j];

        f16x8 bhh[4], bll[4];
        {
            const float* fb = f + (T >> 10) * 65536 + (T & 1023);
#pragma unroll
            for (int ks = 0; ks < 4; ++ks) {
#pragma unroll
                for (int jj = 0; jj < 8; ++jj) {
                    float v = fb[(ks * 16 + g * 8 + jj) * 1024];
                    _Float16 h = (_Float16)v;
                    bhh[ks][jj] = h;
                    bll[ks][jj] = (_Float16)((v - (float)h) * 2048.0f);
                }
            }
        }

        float best = -3.4e38f;
        int   bidx = 0;

#pragma unroll 1
        for (int cv = 0; cv < CH2; ++cv) {
            const _Float16* Ab = cp + (size_t)(seg * 32 + cv) * 4096 + g * 256 + c31 * 8;
            f16x8 Ah0 = *(const f16x8*)(Ab);
            f16x8 Ah1 = *(const f16x8*)(Ab + 512);
            f16x8 Ah2 = *(const f16x8*)(Ab + 1024);
            f16x8 Ah3 = *(const f16x8*)(Ab + 1536);
            f16x8 Al0 = *(const f16x8*)(Ab + 2048);
            f16x8 Al1 = *(const f16x8*)(Ab + 2560);
            f16x8 Al2 = *(const f16x8*)(Ab + 3072);
            f16x8 Al3 = *(const f16x8*)(Ab + 3584);

            f32x16 amA, amB, acA, acB;
            amA = __builtin_amdgcn_mfma_f32_32x32x16_f16(Ah0, bhh[0], zacc, 0, 0, 0);
            amB = __builtin_amdgcn_mfma_f32_32x32x16_f16(Ah2, bhh[2], zacc, 0, 0, 0);
            acA = __builtin_amdgcn_mfma_f32_32x32x16_f16(Ah0, bll[0], zacc, 0, 0, 0);
            acB = __builtin_amdgcn_mfma_f32_32x32x16_f16(Ah2, bll[2], zacc, 0, 0, 0);
            amA = __builtin_amdgcn_mfma_f32_32x32x16_f16(Ah1, bhh[1], amA, 0, 0, 0);
            amB = __builtin_amdgcn_mfma_f32_32x32x16_f16(Ah3, bhh[3], amB, 0, 0, 0);
            acA = __builtin_amdgcn_mfma_f32_32x32x16_f16(Al0, bhh[0], acA, 0, 0, 0);
            acB = __builtin_amdgcn_mfma_f32_32x32x16_f16(Al2, bhh[2], acB, 0, 0, 0);
            acA = __builtin_amdgcn_mfma_f32_32x32x16_f16(Ah1, bll[1], acA, 0, 0, 0);
            acB = __builtin_amdgcn_mfma_f32_32x32x16_f16(Ah3, bll[3], acB, 0, 0, 0);
            acA = __builtin_amdgcn_mfma_f32_32x32x16_f16(Al1, bhh[1], acA, 0, 0, 0);
            acB = __builtin_amdgcn_mfma_f32_32x32x16_f16(Al3, bhh[3], acB, 0, 0, 0);

            const int codebase = seg * VSEG2 + cv * 32;
#pragma unroll
            for (int r = 0; r < 16; ++r) {
                const int codeq = codebase + (r & 3) + 8 * (r >> 2);
                float s = fmaf(acA[r] + acB[r], INV2048, amA[r] + amB[r]);
                bool u = s > best;
                best = u ? s : best;
                bidx = u ? codeq : bidx;
            }
        }

        bidx += 4 * g;
        {
            float ov = __shfl_xor(best, 32);
            int   oi = __shfl_xor(bidx, 32);
            if (ov > best || (ov == best && oi < bidx)) { best = ov; bidx = oi; }
        }
        if (lane < 32) {
            atomicMax(&keys[T], packkey(best, bidx));
        }
    }
}

__global__ __launch_bounds__(256)
void k_finalize(const float* __restrict__ f, const float* __restrict__ w,
                const unsigned long long* __restrict__ keys,
                const int* __restrict__ idxf,
                int* __restrict__ counts, float* __restrict__ blocksq,
                float* __restrict__ out) {
    const int tid = threadIdx.x;
    const int t   = blockIdx.x * 256 + tid;   // token id (coalesced in hw)

    int bi = idxf[t];
    if (bi < 0) bi = 8191 - (int)(unsigned)(keys[t] & 0xFFFFFFFFull);
    atomicAdd(&counts[bi], 1);

    float4 cr[16];
    const float4* crow = (const float4*)(w + bi * C_DIM);
#pragma unroll
    for (int i = 0; i < 16; ++i) cr[i] = crow[i];
    const float* crs = (const float*)cr;

    const int bb = t >> 10;
    const int hw = t & 1023;
    const float* fb = f + bb * 65536 + hw;
    float*       ob = out + bb * 65536 + hw;

    float s = 0.f;
#pragma unroll
    for (int c = 0; c < C_DIM; ++c) {
        float fv = fb[c * 1024];
        float d  = crs[c] - fv;
        s += d * d;
        ob[c * 1024] = fv + d;   // f + sg(fhat - f)
    }

    __shared__ float red[256];
    red[tid] = s;
    __syncthreads();
    for (int st = 128; st > 0; st >>= 1) {
        if (tid < st) red[tid] += red[tid + st];
        __syncthreads();
    }
    if (tid == 0) blocksq[blockIdx.x] = red[0];
}

__global__ __launch_bounds__(256)
void k_stats(const int* __restrict__ counts, const float* __restrict__ blocksq,
             float* __restrict__ out) {
    __shared__ float redf[256];
    __shared__ int   redi[256];
    const int tid = threadIdx.x;
    int used = 0;
    for (int v = tid; v < V_TOTAL; v += 256) used += (counts[v] > 0) ? 1 : 0;
    redi[tid] = used;
    redf[tid] = (tid < 128) ? blocksq[tid] : 0.f;
    __syncthreads();
    for (int st = 128; st > 0; st >>= 1) {
        if (tid < st) { redi[tid] += redi[tid + st]; redf[tid] += redf[tid + st]; }
        __syncthreads();
    }
    if (tid == 0) {
        float mse = redf[0] / 2097152.0f;
        out[2097152] = 0.25f * mse + mse;   // BETA*mean + mean
        out[2097153] = 0.0f;                // entropy_loss
        out[2097154] = 100.0f * (float)redi[0] / 8192.0f;  // vocab_usage
    }
}

extern "C" void kernel_launch(void* const* d_in, const int* in_sizes, int n_in,
                              void* d_out, int out_size, void* d_ws, size_t ws_size,
                              hipStream_t stream) {
    const float* f = (const float*)d_in[0];
    const float* w = (const float*)d_in[1];
    float* out = (float*)d_out;
    float* ws  = (float*)d_ws;

    _Float16*           cp       = (_Float16*)ws;
    float*              m1s      = ws + 524288;
    float*              m2s      = ws + 655360;
    int*                i1s      = (int*)(ws + 786432);
    float*              fn2      = ws + 917504;
    unsigned long long* keys     = (unsigned long long*)(ws + 950272);
    int*                idxf     = (int*)(ws + 1015808);
    int*                unc_list = (int*)(ws + 1048576);
    int*                unc_cnt  = (int*)(ws + 1081344);
    int*                counts   = (int*)(ws + 1081408);
    float*              blocksq  = ws + 1089600;

    hipLaunchKernelGGL(k_prep, dim3(32), dim3(256), 0, stream,
                       w, cp, keys, counts, unc_cnt);
    hipLaunchKernelGGL(k_pass1, dim3(N_TOK / 128, VSPLIT1), dim3(256), 0, stream,
                       f, cp, m1s, m2s, i1s, fn2);
    hipLaunchKernelGGL(k_classify, dim3(N_TOK / 256), dim3(256), 0, stream,
                       m1s, m2s, i1s, fn2, idxf, unc_list, unc_cnt);
    hipLaunchKernelGGL(k_pass2, dim3(256, VSPLIT2), dim3(64), 0, stream,
                       f, cp, unc_list, unc_cnt, keys);
    hipLaunchKernelGGL(k_finalize, dim3(N_TOK / 256), dim3(256), 0, stream,
                       f, w, keys, idxf, counts, blocksq, out);
    hipLaunchKernelGGL(k_stats, dim3(1), dim3(256), 0, stream,
                       counts, blocksq, out);
}